// Round 9
// baseline (3541.290 us; speedup 1.0000x reference)
//
#include <hip/hip_runtime.h>

#define B_   64
#define T_   512
#define IN_  512
#define HID_ 1024
#define OUT_ 512

#define BROW 1092        // hs staging row stride (floats): 1024 data + pads
#define WSTRIDE 272      // per-wave staging stride: 4 c-groups x 68 (>268 span)
#define RED_STRIDE 260   // reduction slice stride (floats)
#define REDSZ (32 * RED_STRIDE)

typedef unsigned long long u64;

// ---------------------------------------------------------------------------
// K0: transpose W_hh [j][k] -> Wt [k][j] so scan W reads are lane-coalesced.
// ---------------------------------------------------------------------------
__global__ __launch_bounds__(256) void transpose_whh(const float* __restrict__ W,
                                                     float* __restrict__ Wt) {
  __shared__ float tile[32][33];
  const int bx = blockIdx.x * 32;  // k
  const int by = blockIdx.y * 32;  // j
  const int tx = threadIdx.x;
  const int ty = threadIdx.y;
#pragma unroll
  for (int i = 0; i < 32; i += 8)
    tile[ty + i][tx] = W[(size_t)(by + ty + i) * HID_ + bx + tx];
  __syncthreads();
#pragma unroll
  for (int i = 0; i < 32; i += 8)
    Wt[(size_t)(bx + ty + i) * HID_ + by + tx] = tile[tx][ty + i];
}

// ---------------------------------------------------------------------------
// K1/K3: C[M,N] = A[M,K] @ B[N,K]^T + bias[N].  fp32, 128x128 tile, BK=8.
// ---------------------------------------------------------------------------
__global__ __launch_bounds__(256) void gemm_bias(const float* __restrict__ A,
                                                 const float* __restrict__ Bm,
                                                 const float* __restrict__ bias,
                                                 float* __restrict__ C,
                                                 int M, int N, int K) {
  __shared__ float As[8][128];
  __shared__ float Bs[8][128];
  const int bm = blockIdx.y * 128;
  const int bn = blockIdx.x * 128;
  const int tid = threadIdx.x;
  const int tr = (tid / 16) * 8;
  const int tc = (tid % 16) * 8;
  const int lr = tid / 2;
  const int lk = (tid % 2) * 4;

  float acc[8][8];
#pragma unroll
  for (int i = 0; i < 8; i++)
#pragma unroll
    for (int j = 0; j < 8; j++) acc[i][j] = 0.f;

  for (int k0 = 0; k0 < K; k0 += 8) {
    float4 a = *(const float4*)&A[(size_t)(bm + lr) * K + k0 + lk];
    float4 b = *(const float4*)&Bm[(size_t)(bn + lr) * K + k0 + lk];
    As[lk + 0][lr] = a.x; As[lk + 1][lr] = a.y;
    As[lk + 2][lr] = a.z; As[lk + 3][lr] = a.w;
    Bs[lk + 0][lr] = b.x; Bs[lk + 1][lr] = b.y;
    Bs[lk + 2][lr] = b.z; Bs[lk + 3][lr] = b.w;
    __syncthreads();
#pragma unroll
    for (int k = 0; k < 8; k++) {
      float av[8], bv[8];
#pragma unroll
      for (int i = 0; i < 8; i++) av[i] = As[k][tr + i];
#pragma unroll
      for (int j = 0; j < 8; j++) bv[j] = Bs[k][tc + j];
#pragma unroll
      for (int i = 0; i < 8; i++)
#pragma unroll
        for (int j = 0; j < 8; j++) acc[i][j] += av[i] * bv[j];
    }
    __syncthreads();
  }

#pragma unroll
  for (int i = 0; i < 8; i++) {
#pragma unroll
    for (int j = 0; j < 8; j += 4) {
      float4 o;
      o.x = acc[i][j + 0] + bias[bn + tc + j + 0];
      o.y = acc[i][j + 1] + bias[bn + tc + j + 1];
      o.z = acc[i][j + 2] + bias[bn + tc + j + 2];
      o.w = acc[i][j + 3] + bias[bn + tc + j + 3];
      *(float4*)&C[(size_t)(bm + tr + i) * N + bn + tc + j] = o;
    }
  }
}

// ---------------------------------------------------------------------------
// K2: persistent scan, epoch-tagged handoff (protocol as scan9/10).
//  (1) CHUNKED poll->compute: each thread's 32 k re-striped across the
//      wave's four 64-k c-groups (8 k each).  Burst-load all 32 tagged u64,
//      then per c-group: validate (gates on 2 producer blocks) -> compute
//      its 256-FMA chunk.  Straggler wait absorbs compute.
//  (2) XCD-local peers: bg = bid&7, jg = bid>>3 (pure permutation).
//  BUGFIX vs R8: per-wave staging stride was 260 < the 268-float span of a
//  wave's four c-groups (4x68 layout) -> wave w's c=3 tail overlapped wave
//  w+1's c=0 head (8 floats/b-row corrupted every step, absmax 0.63).
//  Now WSTRIDE=272 (=4*68); max offset 3*272+204+63 = 1083 < BROW 1092.
// W forced-resident (asm "+v").  Distributed reduce/publish (scan10).
// Deadlock-freedom unchanged.
// ---------------------------------------------------------------------------
__global__ __launch_bounds__(256, 1) void rnn_scan12(const float* __restrict__ Wt,
                                                     float* __restrict__ hall,
                                                     u64* __restrict__ hx) {
  __shared__ float hs[8 * BROW];   // staging, per-wave disjoint column ranges
  __shared__ float red[2 * REDSZ]; // ping-pong partial sums

  const int bid = blockIdx.x;
  const int bg = bid & 7;    // XCD-local peer grouping
  const int jg = bid >> 3;
  const int j0 = jg * 32;
  const int b0 = bg * 8;
  const int tid = threadIdx.x;
  const int q  = tid & 7;
  const int ks = tid >> 3;
  const int wv = tid >> 6;   // wave id 0..3; wave w owns k in [256w,256w+256)
  const int ln = tid & 63;
  const int s8 = ((tid >> 3) & 7) * 8;  // thread's 8-k sub-stripe within a c-group

  // reduce/publish mapping: this lane owns h[rb][rj] of the block's 8x32 tile
  const int rb = 2 * wv + (ln >> 5);  // 0..7
  const int rj = ln & 31;             // 0..31

  const float* hsbase = hs;

  // preload loop-invariant W slice, re-striped: w[c*8+i] is row
  // (wv*256 + c*64 + s8 + i), cols j0+q*4..+3
  float4 w[32];
#pragma unroll
  for (int n = 0; n < 32; ++n) {
    const int row = wv * 256 + (n >> 3) * 64 + s8 + (n & 7);
    w[n] = *(const float4*)(Wt + (size_t)row * HID_ + j0 + q * 4);
  }
  // force residency: opaque asm so the compiler cannot re-load from memory
#pragma unroll
  for (int n = 0; n < 32; ++n)
    __asm__ volatile("" : "+v"(w[n].x), "+v"(w[n].y), "+v"(w[n].z), "+v"(w[n].w));

// stage one c-group: 8 tagged u64 loads, LDS write, tag check
#define STAGE_C(c, okvar)                                                     \
  do {                                                                        \
    const int k_ = wv * 256 + (c)*64 + ln;                                    \
    const int o_ = wv * WSTRIDE + (c)*68 + ln;                                \
    u64 v_[8];                                                                \
    _Pragma("unroll")                                                         \
    for (int b_ = 0; b_ < 8; ++b_)                                            \
      v_[b_] = __hip_atomic_load(src + (size_t)(b0 + b_) * HID_ + k_,         \
                                 __ATOMIC_RELAXED, __HIP_MEMORY_SCOPE_AGENT); \
    bool o2_ = true;                                                          \
    _Pragma("unroll")                                                         \
    for (int b_ = 0; b_ < 8; ++b_) {                                          \
      union { unsigned u; float f; } cv_; cv_.u = (unsigned)v_[b_];           \
      hs[b_ * BROW + o_] = cv_.f;                                             \
      o2_ &= ((v_[b_] >> 32) == wantTag);                                     \
    }                                                                         \
    okvar = o2_;                                                              \
  } while (0)

  for (int t = 0; t < T_; ++t) {
    // --- per-lane xp load for this lane's reduce slot (fires before poll)
    float* hrow = &hall[((size_t)(b0 + rb) * T_ + t) * HID_ + j0 + rj];
    const float xpv = *hrow;

    float4 acc[8];
#pragma unroll
    for (int bi = 0; bi < 8; ++bi) acc[bi] = make_float4(0.f, 0.f, 0.f, 0.f);

    if (t > 0) {
      const u64 wantTag = (u64)(unsigned)(t - 1);
      const u64* src = hx + (size_t)((t - 1) & 1) * (B_ * HID_);

      // --- burst: issue all 4 c-groups once (fills the memory pipe)
      bool ok0, ok1, ok2, ok3;
      STAGE_C(0, ok0); STAGE_C(1, ok1); STAGE_C(2, ok2); STAGE_C(3, ok3);

      // --- per-c: validate (2 producers) then compute the 256-FMA chunk
#pragma unroll
      for (int c = 0; c < 4; ++c) {
        bool okc = (c == 0) ? ok0 : (c == 1) ? ok1 : (c == 2) ? ok2 : ok3;
        while (!__all(okc)) STAGE_C(c, okc);
        __asm__ __volatile__("" ::: "memory");

        const int ob = wv * WSTRIDE + c * 68 + s8;
        const int n = c * 8;
#pragma unroll
        for (int bi = 0; bi < 8; ++bi) {
          const float4 h0 = *(const float4*)(hsbase + bi * BROW + ob);
          const float4 h1 = *(const float4*)(hsbase + bi * BROW + ob + 4);
          acc[bi].x += h0.x * w[n].x + h0.y * w[n + 1].x + h0.z * w[n + 2].x + h0.w * w[n + 3].x
                     + h1.x * w[n + 4].x + h1.y * w[n + 5].x + h1.z * w[n + 6].x + h1.w * w[n + 7].x;
          acc[bi].y += h0.x * w[n].y + h0.y * w[n + 1].y + h0.z * w[n + 2].y + h0.w * w[n + 3].y
                     + h1.x * w[n + 4].y + h1.y * w[n + 5].y + h1.z * w[n + 6].y + h1.w * w[n + 7].y;
          acc[bi].z += h0.x * w[n].z + h0.y * w[n + 1].z + h0.z * w[n + 2].z + h0.w * w[n + 3].z
                     + h1.x * w[n + 4].z + h1.y * w[n + 5].z + h1.z * w[n + 6].z + h1.w * w[n + 7].z;
          acc[bi].w += h0.x * w[n].w + h0.y * w[n + 1].w + h0.z * w[n + 2].w + h0.w * w[n + 3].w
                     + h1.x * w[n + 4].w + h1.y * w[n + 5].w + h1.z * w[n + 6].w + h1.w * w[n + 7].w;
        }
      }
    }

    // --- write partial sums to red[t&1]
    float* redb = red + (t & 1) * REDSZ;
#pragma unroll
    for (int bi = 0; bi < 8; ++bi)
      *(float4*)&redb[ks * RED_STRIDE + bi * 32 + q * 4] = acc[bi];
    __syncthreads();  // THE one barrier: all partials in red before reduce

    // --- distributed reduce: every lane reduces its own h[rb][rj]
    {
      float sum = 0.f;
#pragma unroll
      for (int kss = 0; kss < 32; ++kss)
        sum += redb[kss * RED_STRIDE + rb * 32 + rj];
      const float h = tanhf(sum + xpv);

      // tagged publish: fire-and-forget, no ack, no flag
      union { float f; unsigned u; } cv; cv.f = h;
      u64* dst = hx + (size_t)(t & 1) * (B_ * HID_)
                    + (size_t)(b0 + rb) * HID_ + j0 + rj;
      __hip_atomic_store(dst, (((u64)(unsigned)t) << 32) | (u64)cv.u,
                         __ATOMIC_RELAXED, __HIP_MEMORY_SCOPE_AGENT);
      // plain store for the final GEMM (kernel-end release flushes it)
      *hrow = h;
    }
    // no trailing barrier: red WAR covered by parity + next step's barrier
  }
#undef STAGE_C
}

// ---------------------------------------------------------------------------
extern "C" void kernel_launch(void* const* d_in, const int* in_sizes, int n_in,
                              void* d_out, int out_size, void* d_ws, size_t ws_size,
                              hipStream_t stream) {
  (void)in_sizes; (void)n_in; (void)out_size; (void)ws_size;
  const float* input = (const float*)d_in[0];
  const float* W_ih  = (const float*)d_in[1];
  const float* W_hh  = (const float*)d_in[2];
  const float* bias  = (const float*)d_in[3];
  const float* W_out = (const float*)d_in[4];
  const float* b_out = (const float*)d_in[5];
  float* out = (float*)d_out;

  float* Wt   = (float*)d_ws;                  // 4 MiB
  float* hall = Wt + (size_t)HID_ * HID_;      // 128 MiB (x_proj, then h)
  // hx lives in the head of d_out: 2 x 64 x 1024 x 8 B = 1 MiB, memset to
  // 0xFF (tag 0xFFFFFFFF != any step), overwritten by the final GEMM.
  u64* hx = (u64*)d_out;

  hipMemsetAsync(hx, 0xFF, (size_t)2 * B_ * HID_ * sizeof(u64), stream);

  transpose_whh<<<dim3(32, 32), dim3(32, 8), 0, stream>>>(W_hh, Wt);

  gemm_bias<<<dim3(HID_ / 128, (B_ * T_) / 128), 256, 0, stream>>>(
      input, W_ih, bias, hall, B_ * T_, HID_, IN_);

  rnn_scan12<<<dim3(256), dim3(256), 0, stream>>>(Wt, hall, hx);

  gemm_bias<<<dim3(OUT_ / 128, (B_ * T_) / 128), 256, 0, stream>>>(
      hall, W_out, b_out, out, B_ * T_, OUT_, HID_);
}

// Round 10
// 2847.609 us; speedup vs baseline: 1.2436x; 1.2436x over previous
//
#include <hip/hip_runtime.h>

#define B_   64
#define T_   512
#define IN_  512
#define HID_ 1024
#define OUT_ 512

#define BROW 1092        // hs staging row stride (floats): 1024 data + pads
#define WSTRIDE 272      // per-wave staging stride: 4 c-groups x 68 (>268 span)
#define RED_STRIDE 260   // reduction slice stride (floats)
#define REDSZ (32 * RED_STRIDE)

typedef unsigned long long u64;
typedef __attribute__((ext_vector_type(8))) short short8;
typedef __attribute__((ext_vector_type(4))) float f32x4;

// ---------------------------------------------------------------------------
// K0: transpose W_hh [j][k] -> Wt [k][j] so scan W reads are lane-coalesced.
// ---------------------------------------------------------------------------
__global__ __launch_bounds__(256) void transpose_whh(const float* __restrict__ W,
                                                     float* __restrict__ Wt) {
  __shared__ float tile[32][33];
  const int bx = blockIdx.x * 32;  // k
  const int by = blockIdx.y * 32;  // j
  const int tx = threadIdx.x;
  const int ty = threadIdx.y;
#pragma unroll
  for (int i = 0; i < 32; i += 8)
    tile[ty + i][tx] = W[(size_t)(by + ty + i) * HID_ + bx + tx];
  __syncthreads();
#pragma unroll
  for (int i = 0; i < 32; i += 8)
    Wt[(size_t)(bx + ty + i) * HID_ + by + tx] = tile[tx][ty + i];
}

// ---------------------------------------------------------------------------
// K1/K3: C[M,N] = A[M,K] @ B[N,K]^T + bias[N], via bf16 MFMA (16x16x32).
// Inputs f32, converted RNE->bf16 during LDS staging; fp32 accumulate.
// 128x128 tile, BK=32, 4 waves in 2x2, each wave 4x4 16x16 tiles (64 AGPR).
// LDS rows padded to 40 bf16 (80 B): 16B-aligned b128 frag reads, 2-way
// bank alias only (free).  C layout per m89: col=lane&15, row=(lane>>4)*4+r.
// ---------------------------------------------------------------------------
__device__ inline unsigned short f2bf(float f) {
  unsigned u = __float_as_uint(f);
  u += 0x7FFFu + ((u >> 16) & 1u);   // round-to-nearest-even
  return (unsigned short)(u >> 16);
}

__global__ __launch_bounds__(256) void gemm_bias_mfma(const float* __restrict__ A,
                                                      const float* __restrict__ Bm,
                                                      const float* __restrict__ bias,
                                                      float* __restrict__ C,
                                                      int M, int N, int K) {
  __shared__ unsigned short Al[128 * 40];
  __shared__ unsigned short Bl[128 * 40];
  const int bm = blockIdx.y * 128;
  const int bn = blockIdx.x * 128;
  const int tid = threadIdx.x;
  const int lane = tid & 63;
  const int wv = tid >> 6;
  const int wm = (wv >> 1) * 64;   // wave m-origin within tile
  const int wn = (wv & 1) * 64;    // wave n-origin within tile

  const int srow = tid >> 1;            // staging: row 0..127
  const int scol = (tid & 1) * 16;      // staging: float col 0 or 16

  f32x4 acc[4][4];
#pragma unroll
  for (int i = 0; i < 4; i++)
#pragma unroll
    for (int j = 0; j < 4; j++) acc[i][j] = (f32x4){0.f, 0.f, 0.f, 0.f};

  const float* ap = &A[(size_t)(bm + srow) * K + scol];
  const float* bp = &Bm[(size_t)(bn + srow) * K + scol];
  unsigned short* ad = &Al[srow * 40 + scol];
  unsigned short* bd = &Bl[srow * 40 + scol];

  for (int k0 = 0; k0 < K; k0 += 32) {
    float4 av[4], bv[4];
#pragma unroll
    for (int i = 0; i < 4; i++) av[i] = *(const float4*)(ap + k0 + i * 4);
#pragma unroll
    for (int i = 0; i < 4; i++) bv[i] = *(const float4*)(bp + k0 + i * 4);

    __syncthreads();  // previous iteration's frag reads complete
#pragma unroll
    for (int i = 0; i < 4; i++) {
      ushort4 ta, tb;
      ta.x = f2bf(av[i].x); ta.y = f2bf(av[i].y); ta.z = f2bf(av[i].z); ta.w = f2bf(av[i].w);
      tb.x = f2bf(bv[i].x); tb.y = f2bf(bv[i].y); tb.z = f2bf(bv[i].z); tb.w = f2bf(bv[i].w);
      *(ushort4*)(ad + i * 4) = ta;
      *(ushort4*)(bd + i * 4) = tb;
    }
    __syncthreads();  // tile staged

    short8 af[4], bf[4];
#pragma unroll
    for (int mt = 0; mt < 4; ++mt)
      af[mt] = *(const short8*)&Al[(wm + mt * 16 + (lane & 15)) * 40 + (lane >> 4) * 8];
#pragma unroll
    for (int nt = 0; nt < 4; ++nt)
      bf[nt] = *(const short8*)&Bl[(wn + nt * 16 + (lane & 15)) * 40 + (lane >> 4) * 8];
#pragma unroll
    for (int mt = 0; mt < 4; ++mt)
#pragma unroll
      for (int nt = 0; nt < 4; ++nt)
        acc[mt][nt] = __builtin_amdgcn_mfma_f32_16x16x32_bf16(af[mt], bf[nt],
                                                              acc[mt][nt], 0, 0, 0);
  }

  // epilogue: C[row][col] = acc + bias[col]
#pragma unroll
  for (int nt = 0; nt < 4; ++nt) {
    const int col = bn + wn + nt * 16 + (lane & 15);
    const float bvv = bias[col];
#pragma unroll
    for (int mt = 0; mt < 4; ++mt) {
      const int rowb = bm + wm + mt * 16 + (lane >> 4) * 4;
#pragma unroll
      for (int r = 0; r < 4; ++r)
        C[(size_t)(rowb + r) * N + col] = acc[mt][nt][r] + bvv;
    }
  }
}

// ---------------------------------------------------------------------------
// K2: persistent scan, epoch-tagged handoff (UNCHANGED from rnn_scan12 —
// verified best at ~2.7 ms).  See R8/R9 notes: chunked poll->compute,
// XCD-local peers, W forced-resident, distributed reduce/publish.
// ---------------------------------------------------------------------------
__global__ __launch_bounds__(256, 1) void rnn_scan12(const float* __restrict__ Wt,
                                                     float* __restrict__ hall,
                                                     u64* __restrict__ hx) {
  __shared__ float hs[8 * BROW];   // staging, per-wave disjoint column ranges
  __shared__ float red[2 * REDSZ]; // ping-pong partial sums

  const int bid = blockIdx.x;
  const int bg = bid & 7;    // XCD-local peer grouping
  const int jg = bid >> 3;
  const int j0 = jg * 32;
  const int b0 = bg * 8;
  const int tid = threadIdx.x;
  const int q  = tid & 7;
  const int ks = tid >> 3;
  const int wv = tid >> 6;   // wave id 0..3; wave w owns k in [256w,256w+256)
  const int ln = tid & 63;
  const int s8 = ((tid >> 3) & 7) * 8;  // thread's 8-k sub-stripe within a c-group

  // reduce/publish mapping: this lane owns h[rb][rj] of the block's 8x32 tile
  const int rb = 2 * wv + (ln >> 5);  // 0..7
  const int rj = ln & 31;             // 0..31

  const float* hsbase = hs;

  // preload loop-invariant W slice, re-striped: w[c*8+i] is row
  // (wv*256 + c*64 + s8 + i), cols j0+q*4..+3
  float4 w[32];
#pragma unroll
  for (int n = 0; n < 32; ++n) {
    const int row = wv * 256 + (n >> 3) * 64 + s8 + (n & 7);
    w[n] = *(const float4*)(Wt + (size_t)row * HID_ + j0 + q * 4);
  }
  // force residency: opaque asm so the compiler cannot re-load from memory
#pragma unroll
  for (int n = 0; n < 32; ++n)
    __asm__ volatile("" : "+v"(w[n].x), "+v"(w[n].y), "+v"(w[n].z), "+v"(w[n].w));

// stage one c-group: 8 tagged u64 loads, LDS write, tag check
#define STAGE_C(c, okvar)                                                     \
  do {                                                                        \
    const int k_ = wv * 256 + (c)*64 + ln;                                    \
    const int o_ = wv * WSTRIDE + (c)*68 + ln;                                \
    u64 v_[8];                                                                \
    _Pragma("unroll")                                                         \
    for (int b_ = 0; b_ < 8; ++b_)                                            \
      v_[b_] = __hip_atomic_load(src + (size_t)(b0 + b_) * HID_ + k_,         \
                                 __ATOMIC_RELAXED, __HIP_MEMORY_SCOPE_AGENT); \
    bool o2_ = true;                                                          \
    _Pragma("unroll")                                                         \
    for (int b_ = 0; b_ < 8; ++b_) {                                          \
      union { unsigned u; float f; } cv_; cv_.u = (unsigned)v_[b_];           \
      hs[b_ * BROW + o_] = cv_.f;                                             \
      o2_ &= ((v_[b_] >> 32) == wantTag);                                     \
    }                                                                         \
    okvar = o2_;                                                              \
  } while (0)

  for (int t = 0; t < T_; ++t) {
    // --- per-lane xp load for this lane's reduce slot (fires before poll)
    float* hrow = &hall[((size_t)(b0 + rb) * T_ + t) * HID_ + j0 + rj];
    const float xpv = *hrow;

    float4 acc[8];
#pragma unroll
    for (int bi = 0; bi < 8; ++bi) acc[bi] = make_float4(0.f, 0.f, 0.f, 0.f);

    if (t > 0) {
      const u64 wantTag = (u64)(unsigned)(t - 1);
      const u64* src = hx + (size_t)((t - 1) & 1) * (B_ * HID_);

      // --- burst: issue all 4 c-groups once (fills the memory pipe)
      bool ok0, ok1, ok2, ok3;
      STAGE_C(0, ok0); STAGE_C(1, ok1); STAGE_C(2, ok2); STAGE_C(3, ok3);

      // --- per-c: validate (2 producers) then compute the 256-FMA chunk
#pragma unroll
      for (int c = 0; c < 4; ++c) {
        bool okc = (c == 0) ? ok0 : (c == 1) ? ok1 : (c == 2) ? ok2 : ok3;
        while (!__all(okc)) STAGE_C(c, okc);
        __asm__ __volatile__("" ::: "memory");

        const int ob = wv * WSTRIDE + c * 68 + s8;
        const int n = c * 8;
#pragma unroll
        for (int bi = 0; bi < 8; ++bi) {
          const float4 h0 = *(const float4*)(hsbase + bi * BROW + ob);
          const float4 h1 = *(const float4*)(hsbase + bi * BROW + ob + 4);
          acc[bi].x += h0.x * w[n].x + h0.y * w[n + 1].x + h0.z * w[n + 2].x + h0.w * w[n + 3].x
                     + h1.x * w[n + 4].x + h1.y * w[n + 5].x + h1.z * w[n + 6].x + h1.w * w[n + 7].x;
          acc[bi].y += h0.x * w[n].y + h0.y * w[n + 1].y + h0.z * w[n + 2].y + h0.w * w[n + 3].y
                     + h1.x * w[n + 4].y + h1.y * w[n + 5].y + h1.z * w[n + 6].y + h1.w * w[n + 7].y;
          acc[bi].z += h0.x * w[n].z + h0.y * w[n + 1].z + h0.z * w[n + 2].z + h0.w * w[n + 3].z
                     + h1.x * w[n + 4].z + h1.y * w[n + 5].z + h1.z * w[n + 6].z + h1.w * w[n + 7].z;
          acc[bi].w += h0.x * w[n].w + h0.y * w[n + 1].w + h0.z * w[n + 2].w + h0.w * w[n + 3].w
                     + h1.x * w[n + 4].w + h1.y * w[n + 5].w + h1.z * w[n + 6].w + h1.w * w[n + 7].w;
        }
      }
    }

    // --- write partial sums to red[t&1]
    float* redb = red + (t & 1) * REDSZ;
#pragma unroll
    for (int bi = 0; bi < 8; ++bi)
      *(float4*)&redb[ks * RED_STRIDE + bi * 32 + q * 4] = acc[bi];
    __syncthreads();  // THE one barrier: all partials in red before reduce

    // --- distributed reduce: every lane reduces its own h[rb][rj]
    {
      float sum = 0.f;
#pragma unroll
      for (int kss = 0; kss < 32; ++kss)
        sum += redb[kss * RED_STRIDE + rb * 32 + rj];
      const float h = tanhf(sum + xpv);

      // tagged publish: fire-and-forget, no ack, no flag
      union { float f; unsigned u; } cv; cv.f = h;
      u64* dst = hx + (size_t)(t & 1) * (B_ * HID_)
                    + (size_t)(b0 + rb) * HID_ + j0 + rj;
      __hip_atomic_store(dst, (((u64)(unsigned)t) << 32) | (u64)cv.u,
                         __ATOMIC_RELAXED, __HIP_MEMORY_SCOPE_AGENT);
      // plain store for the final GEMM (kernel-end release flushes it)
      *hrow = h;
    }
    // no trailing barrier: red WAR covered by parity + next step's barrier
  }
#undef STAGE_C
}

// ---------------------------------------------------------------------------
extern "C" void kernel_launch(void* const* d_in, const int* in_sizes, int n_in,
                              void* d_out, int out_size, void* d_ws, size_t ws_size,
                              hipStream_t stream) {
  (void)in_sizes; (void)n_in; (void)out_size; (void)ws_size;
  const float* input = (const float*)d_in[0];
  const float* W_ih  = (const float*)d_in[1];
  const float* W_hh  = (const float*)d_in[2];
  const float* bias  = (const float*)d_in[3];
  const float* W_out = (const float*)d_in[4];
  const float* b_out = (const float*)d_in[5];
  float* out = (float*)d_out;

  float* Wt   = (float*)d_ws;                  // 4 MiB
  float* hall = Wt + (size_t)HID_ * HID_;      // 128 MiB (x_proj, then h)
  // hx lives in the head of d_out: 2 x 64 x 1024 x 8 B = 1 MiB, memset to
  // 0xFF (tag 0xFFFFFFFF != any step), overwritten by the final GEMM.
  u64* hx = (u64*)d_out;

  hipMemsetAsync(hx, 0xFF, (size_t)2 * B_ * HID_ * sizeof(u64), stream);

  transpose_whh<<<dim3(32, 32), dim3(32, 8), 0, stream>>>(W_hh, Wt);

  gemm_bias_mfma<<<dim3(HID_ / 128, (B_ * T_) / 128), 256, 0, stream>>>(
      input, W_ih, bias, hall, B_ * T_, HID_, IN_);

  rnn_scan12<<<dim3(256), dim3(256), 0, stream>>>(Wt, hall, hx);

  gemm_bias_mfma<<<dim3(OUT_ / 128, (B_ * T_) / 128), 256, 0, stream>>>(
      hall, W_out, b_out, out, B_ * T_, OUT_, HID_);
}